// Round 4
// baseline (306.318 us; speedup 1.0000x reference)
//
#include <hip/hip_runtime.h>

// Problem constants (match reference)
#define BB 2
#define CC 64
#define HH 512
#define WW 512
#define NN 4096
#define KK 5
#define HWp (HH * WW)
#define NBLK_LOSS 2048

// ---------------------------------------------------------------------------
// Pass 1: gather sampled feature vectors into compact [B][N][C] buffers.
// wave = (sel, b, point-group g, 8-channel chunk). lane = point.
//  - 8 independent strided gathers per lane in flight; 2048 waves = 8/CU
//    (more waves than round-3's 1024 -> overlaps store/exit tails)
//  - lane's 8 results -> two float4 stores to one 64 B line (coalesced)
//  - lane addresses within one load have random low bits (lin) -> requests
//    spread across HBM channels / L2 banks
// Also zeroes the loss-pass ticket counter (visible via kernel boundary).
// ---------------------------------------------------------------------------
__global__ __launch_bounds__(256) void gather_kernel(
    const float* __restrict__ inputs_ref,
    const float* __restrict__ inputs_other,
    const int*   __restrict__ inds_ref,
    const int*   __restrict__ inds_other,
    float*       __restrict__ Fr,      // [B][N][C]
    float*       __restrict__ Fo,      // [B][N][C]
    int*         __restrict__ ticket)
{
    if (blockIdx.x == 0 && threadIdx.x == 0) *ticket = 0;

    const int lane = threadIdx.x & 63;
    int w = (blockIdx.x * 256 + threadIdx.x) >> 6;   // wave id, 0..2047
    const int chunk = w & 7;  w >>= 3;   // 8 chunks of 8 channels
    const int g     = w & 63; w >>= 6;   // N/64 = 64 point groups
    const int b     = w & 1;  w >>= 1;   // B = 2
    const int sel   = w;                 // 0 = ref, 1 = other

    const int i = g * 64 + lane;
    const int* ind = (sel ? inds_other : inds_ref) + b * 2 * NN;
    const int lin = HH * ind[NN + i] + ind[i];       // H*y + x

    const float* src = (sel ? inputs_other : inputs_ref)
                       + (size_t)b * CC * HWp
                       + (size_t)chunk * 8 * HWp
                       + lin;
    float v[8];
#pragma unroll
    for (int cc = 0; cc < 8; ++cc)
        v[cc] = src[(size_t)cc * HWp];               // 8 independent gathers

    float* dst = (sel ? Fo : Fr) + (size_t)(b * NN + i) * CC + chunk * 8;
    ((float4*)dst)[0] = make_float4(v[0], v[1], v[2], v[3]);
    ((float4*)dst)[1] = make_float4(v[4], v[5], v[6], v[7]);
}

// ---------------------------------------------------------------------------
// Pass 2: one wave per match point, lane = channel. All 7 feature vectors are
// contiguous 256 B reads from the compact L2/L3-resident buffers. Per-block
// partial -> agent-scope release store; last block (ticket) reduces the 2048
// partials and writes out[0] directly (no zero kernel, no reduce kernel).
// ---------------------------------------------------------------------------
__global__ __launch_bounds__(256) void loss_kernel(
    const float* __restrict__ Fr,
    const float* __restrict__ Fo,
    const float* __restrict__ weights,
    const int*   __restrict__ inds_ref,
    const int*   __restrict__ rand_inds,
    float*       __restrict__ partials,   // [NBLK_LOSS]
    int*         __restrict__ ticket,
    float*       __restrict__ out)
{
    const int tid  = threadIdx.x;
    const int lane = tid & 63;
    const int wave = tid >> 6;                 // 4 waves / block
    const int gidx = blockIdx.x * 4 + wave;    // point index in [0, B*N)
    const int b = gidx / NN;
    const int i = gidx - b * NN;

    const int* ir = inds_ref + b * 2 * NN;     // x at [i], y at [NN+i]
    const int xr = ir[i];
    const int yr = ir[NN + i];
    const int* rj = rand_inds + (size_t)(b * NN + i) * KK;

    const float fr = Fr[(size_t)(b * NN + i) * CC + lane];
    const float fo = Fo[(size_t)(b * NN + i) * CC + lane];

    float s[1 + KK];
    float dist[KK];
    { const float d = fr - fo; s[0] = d * d; }
#pragma unroll
    for (int k = 0; k < KK; ++k) {
        const int j = rj[k];                               // wave-uniform
        const float fm = Fo[(size_t)(b * NN + j) * CC + lane];
        const float t = fr - fm;
        s[1 + k] = t * t;
        const float dx = (float)(xr - ir[j]);
        const float dy = (float)(yr - ir[NN + j]);
        dist[k] = sqrtf(dx * dx + dy * dy);
    }

    // 64-lane sum reductions for the 6 squared feature distances
#pragma unroll
    for (int r = 0; r < 1 + KK; ++r) {
        float v = s[r];
#pragma unroll
        for (int off = 32; off > 0; off >>= 1)
            v += __shfl_xor(v, off, 64);
        s[r] = v;
    }

    __shared__ float part[4];
    __shared__ int last;
    if (lane == 0) {
        const float max_distance = 724.07734f;   // sqrt(512^2+512^2)
        const float thr_nomatch  = 16.0f;        // 0.5^2 * C
        float acc = weights[b * NN + i] * fmaxf(s[0], 0.0f);
#pragma unroll
        for (int k = 0; k < KK; ++k) {
            // w_mm = -NON_MATCH_WEIGHT * d / max_dist / K, weight==K==5
            acc += (-dist[k] / max_distance) * fminf(s[1 + k], thr_nomatch);
        }
        part[wave] = acc * (1.0f / (float)((KK + 1) * NN));
    }
    __syncthreads();
    if (tid == 0) {
        const float p = part[0] + part[1] + part[2] + part[3];
        // agent-scope release: make the partial visible across XCD L2s
        __hip_atomic_store(&partials[blockIdx.x], p,
                           __ATOMIC_RELEASE, __HIP_MEMORY_SCOPE_AGENT);
        const int old = __hip_atomic_fetch_add(ticket, 1,
                           __ATOMIC_ACQ_REL, __HIP_MEMORY_SCOPE_AGENT);
        last = (old == NBLK_LOSS - 1);           // acquire: caches invalidated
    }
    __syncthreads();

    if (last) {                                  // exactly one block
        float v = 0.0f;
        for (int idx = tid; idx < NBLK_LOSS; idx += 256)
            v += partials[idx];
#pragma unroll
        for (int off = 32; off > 0; off >>= 1)
            v += __shfl_xor(v, off, 64);
        if (lane == 0) part[wave] = v;
        __syncthreads();
        if (tid == 0)
            out[0] = part[0] + part[1] + part[2] + part[3];
    }
}

extern "C" void kernel_launch(void* const* d_in, const int* in_sizes, int n_in,
                              void* d_out, int out_size, void* d_ws, size_t ws_size,
                              hipStream_t stream) {
    const float* inputs_ref   = (const float*)d_in[0];
    const float* inputs_other = (const float*)d_in[1];
    const float* weights      = (const float*)d_in[2];
    const int*   inds_ref     = (const int*)d_in[3];
    const int*   inds_other   = (const int*)d_in[4];
    const int*   rand_inds    = (const int*)d_in[5];
    float* out = (float*)d_out;

    // ws layout: Fr [B][N][C], Fo [B][N][C] (2 MB each), partials, ticket
    float* Fr = (float*)d_ws;
    float* Fo = Fr + (size_t)BB * NN * CC;
    float* partials = Fo + (size_t)BB * NN * CC;
    int*   ticket   = (int*)(partials + NBLK_LOSS);

    // pass 1: 2(sel)*2(b)*64(g)*8(chunk) = 2048 waves -> 512 blocks
    gather_kernel<<<512, 256, 0, stream>>>(
        inputs_ref, inputs_other, inds_ref, inds_other, Fr, Fo, ticket);

    // pass 2: B*N = 8192 waves -> 2048 blocks; last block writes out[0]
    loss_kernel<<<NBLK_LOSS, 256, 0, stream>>>(
        Fr, Fo, weights, inds_ref, rand_inds, partials, ticket, out);
}

// Round 5
// 245.857 us; speedup vs baseline: 1.2459x; 1.2459x over previous
//
#include <hip/hip_runtime.h>

// Problem constants (match reference)
#define BB 2
#define CC 64
#define HH 512
#define WW 512
#define NN 4096
#define KK 5
#define HWp (HH * WW)

// ---------------------------------------------------------------------------
// Pass 1: gather sampled feature vectors into compact [B][N][C] buffers.
// wave = (sel, b, point-group g, channel-chunk of 16). lane = point.
//  - 16 independent strided gathers per lane in flight (latency hiding)
//  - lane's 16 results -> four float4 stores to ONE 64 B line (coalesced)
//  - lane addresses within one load have random low bits (lin) -> requests
//    spread across HBM channels / L2 banks
//  - feature reads are NONTEMPORAL: single-use random lines must not evict
//    the 4 MB Fr/Fo buffers from the 4 MiB/XCD L2 (the loss pass re-reads
//    Fr/Fo 7x; keeping them L2-resident is worth more than caching streams)
// NOTE (round-4 post-mortem): do NOT use per-block agent-scope acq/rel here
// or in the loss pass — each pair costs a full L2 writeback/invalidate on
// gfx950 (non-coherent per-XCD L2s); 2048 of them cost +46 us. The implicit
// kernel-boundary flush is the cheap way to pass data between passes.
// ---------------------------------------------------------------------------
__global__ __launch_bounds__(256) void gather_kernel(
    const float* __restrict__ inputs_ref,
    const float* __restrict__ inputs_other,
    const int*   __restrict__ inds_ref,
    const int*   __restrict__ inds_other,
    float*       __restrict__ Fr,      // [B][N][C]
    float*       __restrict__ Fo)      // [B][N][C]
{
    const int lane = threadIdx.x & 63;
    int w = (blockIdx.x * 256 + threadIdx.x) >> 6;   // wave id, 0..1023
    const int chunk = w & 3;  w >>= 2;   // 4 chunks of 16 channels
    const int g     = w & 63; w >>= 6;   // N/64 = 64 point groups
    const int b     = w & 1;  w >>= 1;   // B = 2
    const int sel   = w;                 // 0 = ref, 1 = other

    const int i = g * 64 + lane;
    const int* ind = (sel ? inds_other : inds_ref) + b * 2 * NN;
    const int lin = HH * ind[NN + i] + ind[i];       // H*y + x

    const float* src = (sel ? inputs_other : inputs_ref)
                       + (size_t)b * CC * HWp
                       + (size_t)chunk * 16 * HWp
                       + lin;
    float v[16];
#pragma unroll
    for (int cc = 0; cc < 16; ++cc)
        v[cc] = __builtin_nontemporal_load(src + (size_t)cc * HWp);

    float* dst = (sel ? Fo : Fr) + (size_t)(b * NN + i) * CC + chunk * 16;
#pragma unroll
    for (int q = 0; q < 4; ++q)
        ((float4*)dst)[q] = make_float4(v[4*q], v[4*q+1], v[4*q+2], v[4*q+3]);
}

// ---------------------------------------------------------------------------
// Pass 2: one wave per match point, lane = channel. All 7 feature vectors are
// contiguous 256 B reads from the compact L2-resident buffers (the 5 mismatch
// vectors are re-gathers of Fo at partner points j = rand_inds[i][k]).
// Per-block partial written to ws (no global atomics, no agent-scope fences).
// ---------------------------------------------------------------------------
__global__ __launch_bounds__(256) void loss_kernel(
    const float* __restrict__ Fr,
    const float* __restrict__ Fo,
    const float* __restrict__ weights,
    const int*   __restrict__ inds_ref,
    const int*   __restrict__ rand_inds,
    float*       __restrict__ partials)  // [gridDim.x]
{
    const int tid  = threadIdx.x;
    const int lane = tid & 63;
    const int wave = tid >> 6;                 // 4 waves / block
    const int gidx = blockIdx.x * 4 + wave;    // point index in [0, B*N)
    const int b = gidx / NN;
    const int i = gidx - b * NN;

    const int* ir = inds_ref + b * 2 * NN;     // x at [i], y at [NN+i]
    const int xr = ir[i];
    const int yr = ir[NN + i];
    const int* rj = rand_inds + (size_t)(b * NN + i) * KK;

    const float fr = Fr[(size_t)(b * NN + i) * CC + lane];
    const float fo = Fo[(size_t)(b * NN + i) * CC + lane];

    float s[1 + KK];
    float dist[KK];
    { const float d = fr - fo; s[0] = d * d; }
#pragma unroll
    for (int k = 0; k < KK; ++k) {
        const int j = rj[k];                               // wave-uniform
        const float fm = Fo[(size_t)(b * NN + j) * CC + lane];
        const float t = fr - fm;
        s[1 + k] = t * t;
        const float dx = (float)(xr - ir[j]);
        const float dy = (float)(yr - ir[NN + j]);
        dist[k] = sqrtf(dx * dx + dy * dy);
    }

    // 64-lane sum reductions for the 6 squared feature distances
#pragma unroll
    for (int r = 0; r < 1 + KK; ++r) {
        float v = s[r];
#pragma unroll
        for (int off = 32; off > 0; off >>= 1)
            v += __shfl_xor(v, off, 64);
        s[r] = v;
    }

    __shared__ float part[4];
    if (lane == 0) {
        const float max_distance = 724.07734f;   // sqrt(512^2+512^2)
        const float thr_nomatch  = 16.0f;        // 0.5^2 * C
        float acc = weights[b * NN + i] * fmaxf(s[0], 0.0f);
#pragma unroll
        for (int k = 0; k < KK; ++k) {
            // w_mm = -NON_MATCH_WEIGHT * d / max_dist / K, weight==K==5
            acc += (-dist[k] / max_distance) * fminf(s[1 + k], thr_nomatch);
        }
        part[wave] = acc * (1.0f / (float)((KK + 1) * NN));
    }
    __syncthreads();
    if (tid == 0)
        partials[blockIdx.x] = part[0] + part[1] + part[2] + part[3];
}

// ---------------------------------------------------------------------------
// Final: one block reduces the 2048 per-block partials and writes out[0]
// (overwrites the harness's 0xAA poison; no zero kernel needed).
// ---------------------------------------------------------------------------
__global__ __launch_bounds__(256) void reduce_kernel(
    const float* __restrict__ partials, int n, float* __restrict__ out)
{
    const int tid = threadIdx.x;
    float v = 0.0f;
    for (int idx = tid; idx < n; idx += 256)
        v += partials[idx];
#pragma unroll
    for (int off = 32; off > 0; off >>= 1)
        v += __shfl_xor(v, off, 64);
    __shared__ float part[4];
    if ((tid & 63) == 0) part[tid >> 6] = v;
    __syncthreads();
    if (tid == 0)
        out[0] = part[0] + part[1] + part[2] + part[3];
}

extern "C" void kernel_launch(void* const* d_in, const int* in_sizes, int n_in,
                              void* d_out, int out_size, void* d_ws, size_t ws_size,
                              hipStream_t stream) {
    const float* inputs_ref   = (const float*)d_in[0];
    const float* inputs_other = (const float*)d_in[1];
    const float* weights      = (const float*)d_in[2];
    const int*   inds_ref     = (const int*)d_in[3];
    const int*   inds_other   = (const int*)d_in[4];
    const int*   rand_inds    = (const int*)d_in[5];
    float* out = (float*)d_out;

    // workspace layout: Fr [B][N][C], Fo [B][N][C] (2 MB each), partials 8 KB
    float* Fr = (float*)d_ws;
    float* Fo = Fr + (size_t)BB * NN * CC;
    float* partials = Fo + (size_t)BB * NN * CC;

    // pass 1: 2(sel)*2(b)*64(g)*4(chunk) = 1024 waves -> 256 blocks
    gather_kernel<<<256, 256, 0, stream>>>(
        inputs_ref, inputs_other, inds_ref, inds_other, Fr, Fo);

    // pass 2: B*N = 8192 waves -> 2048 blocks, per-block partials
    loss_kernel<<<2048, 256, 0, stream>>>(
        Fr, Fo, weights, inds_ref, rand_inds, partials);

    // pass 3: single-block tree reduction -> out[0]
    reduce_kernel<<<1, 256, 0, stream>>>(partials, 2048, out);
}